// Round 17
// baseline (394.543 us; speedup 1.0000x reference)
//
#include <hip/hip_runtime.h>
#include <hip/hip_bf16.h>
#include <stdint.h>

#define BATCH_N 65536
#define KDIM 1024
#define NTOT 1536

typedef long long i64;
typedef i64 i64x2 __attribute__((ext_vector_type(2)));
typedef float f32x4 __attribute__((ext_vector_type(4)));

// pack 4 floats (scaled) into 4 fp8-e4m3 bytes
__device__ __forceinline__ unsigned pk4(float4 f, float s) {
    int w = __builtin_amdgcn_cvt_pk_fp8_f32(f.x * s, f.y * s, 0, false);
    w = __builtin_amdgcn_cvt_pk_fp8_f32(f.z * s, f.w * s, w, true);
    return (unsigned)w;
}

// ---------------------------------------------------------------------------
// fp8 k-permuted row layout (per 64-B K-tile, row index m = row&3):
//   byte position P = kt*64 + 16*(g ^ m) + 8*u + low  holds  k = kt*64 +
//   32*u + 8*g + low   (g=0..3, u=0..1, low=0..7).
//   GEMM fragment read: lane (r16, g=lane>>4) reads ONE aligned 16-B word at
//   row*64 + 16*(g ^ (r16&3)) -> {kk0 8B, kk1 8B}.  Bank-quad = 16*(r16&1) +
//   4*(g^(r16&3)): uniform 8 lanes/quad -> conflict-free (r16 fix).
// ---------------------------------------------------------------------------

// Kernel 1: E[b][k] = emb[id_b][k]*64 fp8, permuted layout; rs[b] = rowsum.
__global__ __launch_bounds__(256) void prep_kernel(
    const int* __restrict__ ids,
    const float* __restrict__ mem,
    const float* __restrict__ emb,
    unsigned char* __restrict__ x,
    float* __restrict__ rs)
{
    const int b    = blockIdx.x * 4 + (threadIdx.x >> 6);
    const int lane = threadIdx.x & 63;
    const int id   = ids[b];
    const float4* m4 = (const float4*)(mem + (size_t)id * KDIM) + lane;
    float4 v0 = m4[0], v1 = m4[64], v2 = m4[128], v3 = m4[192];
    float s = (v0.x + v0.y + v0.z + v0.w) + (v1.x + v1.y + v1.z + v1.w)
            + (v2.x + v2.y + v2.z + v2.w) + (v3.x + v3.y + v3.z + v3.w);
    #pragma unroll
    for (int off = 1; off < 64; off <<= 1) s += __shfl_xor(s, off, 64);
    if (lane == 0) rs[b] = s;

    // lane owns k = lane*16 .. +15:  kt = lane>>2, u = (lane>>1)&1,
    // halves h=0,1 -> g = 2*(lane&1) + h
    const float4* e4 = (const float4*)(emb + (size_t)id * KDIM) + lane * 4;
    float4 f0 = e4[0], f1 = e4[1], f2 = e4[2], f3 = e4[3];
    uint2 half0 = {pk4(f0, 64.f), pk4(f1, 64.f)};   // k +0..7
    uint2 half1 = {pk4(f2, 64.f), pk4(f3, 64.f)};   // k +8..15
    const int kt = lane >> 2;
    const int u  = (lane >> 1) & 1;
    const int g0 = 2 * (lane & 1);
    const int m  = b & 3;
    unsigned char* rowp = x + (size_t)b * KDIM + kt * 64 + 8 * u;
    *(uint2*)(rowp + 16 * (g0 ^ m))       = half0;
    *(uint2*)(rowp + 16 * ((g0 + 1) ^ m)) = half1;
}

// Kernel 2: Wt[n] = W_{n/512}[.][n%512]*64 fp8, same permuted layout (m=n&3).
__global__ __launch_bounds__(256) void wconv_kernel(
    const float* __restrict__ Wq, const float* __restrict__ Ws,
    const float* __restrict__ Wk, unsigned char* __restrict__ wt)
{
    const int gt  = blockIdx.x * 256 + threadIdx.x;   // 0..393215
    const int n   = gt % NTOT;
    const int kb4 = (gt / NTOT) * 4;
    const float* W = (n < 512) ? Wq : ((n < 1024) ? Ws : Wk);
    const int nn = n & 511;
    float4 f;
    f.x = W[(size_t)(kb4 + 0) * 512 + nn];
    f.y = W[(size_t)(kb4 + 1) * 512 + nn];
    f.z = W[(size_t)(kb4 + 2) * 512 + nn];
    f.w = W[(size_t)(kb4 + 3) * 512 + nn];
    const unsigned w = pk4(f, 64.f);
    const int kt = kb4 >> 6, kl = kb4 & 63;
    const int u = (kl >> 5) & 1, g = (kl >> 3) & 3, low = kl & 7;
    const int dst = kt * 64 + 16 * (g ^ (n & 3)) + 8 * u + low;
    *(unsigned*)(wt + (size_t)n * KDIM + dst) = w;
}

// Kernel 2b: csum[n] = colsum of W (fp32, deterministic).
__global__ __launch_bounds__(256) void colsum_kernel(
    const float* __restrict__ Wq, const float* __restrict__ Ws,
    const float* __restrict__ Wk, float* __restrict__ csum)
{
    const int gt = blockIdx.x * 256 + threadIdx.x;   // 0..1535
    const float* W = (gt < 512) ? Wq : ((gt < 1024) ? Ws : Wk);
    const int n = gt & 511;
    float s0 = 0.f, s1 = 0.f, s2 = 0.f, s3 = 0.f;
    #pragma unroll 4
    for (int k = 0; k < 1024; k += 4) {
        s0 += W[(size_t)(k + 0) * 512 + n];
        s1 += W[(size_t)(k + 1) * 512 + n];
        s2 += W[(size_t)(k + 2) * 512 + n];
        s3 += W[(size_t)(k + 3) * 512 + n];
    }
    csum[gt] = (s0 + s1) + (s2 + s3);
}

// ---------------------------------------------------------------------------
// Kernel 3: 256x256 8-phase fp8 GEMM (r16's verified skeleton; fragment reads
// now one b128 per pair, conflict-free) + rank-1 + bias + sigmoid.
//   out = sigmoid( (E@W_fp8)*2^-12 + rs*csum + bias )
//   VM2 at P3/P7 (1 DMA/half-tile): at P3 in-flight={P1,P2,P3}, retires
//   B10(odd)+older -> tile o complete before P4's post-barrier reads; at P7
//   retires P2..P5 = tile 2t+2.  Counted waits only, never 0 mid-loop.
// ---------------------------------------------------------------------------
#define BM 256
#define BN 256
#define MT (BATCH_N / BM)   // 256
#define NT (NTOT / BN)      // 6
#define NWG (MT * NT)       // 1536 = 8 * 192, 192 % 6 == 0 -> bijective

#define BAR() asm volatile("s_barrier" ::: "memory")
#define VM2() asm volatile("s_waitcnt vmcnt(2)" ::: "memory")
#define VM0() asm volatile("s_waitcnt vmcnt(0)" ::: "memory")
#define AS1 __attribute__((address_space(1)))
#define AS3 __attribute__((address_space(3)))

__global__ __launch_bounds__(512, 2) void gemm_kernel(
    const unsigned char* __restrict__ X,    // [65536][1024] fp8, permuted
    const unsigned char* __restrict__ Wt,   // [1536][1024]  fp8, permuted
    const float* __restrict__ csum,         // [1536]
    const float* __restrict__ rs,           // [65536]
    const float* __restrict__ bq, const float* __restrict__ bs,
    const float* __restrict__ bk, float* __restrict__ out)
{
    __shared__ __align__(16) unsigned char sA[32768];   // 32 KiB
    __shared__ __align__(16) unsigned char sB[32768];   // 32 KiB

    const int tid  = threadIdx.x;
    const int xcd  = blockIdx.x & 7;
    const int idx  = blockIdx.x >> 3;
    const int wgid = xcd * (NWG / 8) + idx;
    const int nt   = wgid % NT;              // n fastest: A-panel L2 reuse
    const int mt   = wgid / NT;
    const int m0   = mt * BM;
    const int n0   = nt * BN;
    const int wid  = tid >> 6;
    const int lane = tid & 63;
    const int wm   = wid >> 2;               // 0..1
    const int wn   = wid & 3;                // 0..3
    const int r16  = lane & 15;
    const int gk   = lane >> 4;              // 0..3 k-group
    const int fsw  = 16 * (gk ^ (r16 & 3));  // fragment-pair byte-in-row

    f32x4 acc[8][4];
    #pragma unroll
    for (int i = 0; i < 8; i++)
        #pragma unroll
        for (int j = 0; j < 4; j++)
            acc[i][j] = f32x4{0.f, 0.f, 0.f, 0.f};

    i64 af0[4][2], af1[4][2], bfr0[2][2], bfr1[2][2];

    // staging source: row = tid>>2, 16B chunk = tid&3 (layout already permuted)
    const unsigned char* gA = X  + (size_t)(m0 + (tid >> 2)) * KDIM + (tid & 3) * 16;
    const unsigned char* gB = Wt + (size_t)(n0 + (tid >> 2)) * KDIM + (tid & 3) * 16;
    const int ldst = tid * 16;               // linear LDS dest

// stage ONE half-tile (1 DMA instr/thread, 128 rows x 64 B)
#define STG_A(slot, h, kt) \
    __builtin_amdgcn_global_load_lds( \
        (const AS1 void*)(gA + (size_t)(h) * 128 * KDIM + (kt) * 64), \
        (AS3 void*)(&sA[((slot) * 2 + (h)) * 8192 + ldst]), 16, 0, 0)
#define STG_B(slot, h, kt) \
    __builtin_amdgcn_global_load_lds( \
        (const AS1 void*)(gB + (size_t)(h) * 128 * KDIM + (kt) * 64), \
        (AS3 void*)(&sB[((slot) * 2 + (h)) * 8192 + ldst]), 16, 0, 0)

#define LDA(SET, slot, qa) do {                                                 \
    const char* p = (const char*)&sA[((slot) * 2 + (qa)) * 8192];                \
    _Pragma("unroll")                                                            \
    for (int i = 0; i < 4; ++i) {                                                \
        i64x2 v = *(const i64x2*)(p + (wm * 64 + i * 16 + r16) * 64 + fsw);      \
        SET[i][0] = v[0]; SET[i][1] = v[1];                                      \
    }                                                                            \
} while (0)
#define LDB(SET, slot, qb) do {                                                 \
    const char* p = (const char*)&sB[((slot) * 2 + (qb)) * 8192];                \
    _Pragma("unroll")                                                            \
    for (int j = 0; j < 2; ++j) {                                                \
        i64x2 v = *(const i64x2*)(p + (wn * 32 + j * 16 + r16) * 64 + fsw);      \
        SET[j][0] = v[0]; SET[j][1] = v[1];                                      \
    }                                                                            \
} while (0)

#define MM(QA, QB, ASET, BSET) do {                                             \
    __builtin_amdgcn_s_setprio(1);                                               \
    _Pragma("unroll")                                                            \
    for (int i = 0; i < 4; ++i)                                                  \
        _Pragma("unroll")                                                        \
        for (int j = 0; j < 2; ++j)                                              \
            _Pragma("unroll")                                                    \
            for (int kk = 0; kk < 2; ++kk)                                       \
                acc[(QA) * 4 + i][(QB) * 2 + j] =                                \
                    __builtin_amdgcn_mfma_f32_16x16x32_fp8_fp8(                  \
                        ASET[i][kk], BSET[j][kk],                                \
                        acc[(QA) * 4 + i][(QB) * 2 + j], 0, 0, 0);               \
    __builtin_amdgcn_s_setprio(0);                                               \
} while (0)

    // ---- prologue: tile0 full (s0) + tile1 {Ah0,Bh1,Ah1} (s1) ----
    STG_A(0, 0, 0); STG_A(0, 1, 0); STG_B(0, 0, 0); STG_B(0, 1, 0);
    STG_A(1, 0, 1); STG_B(1, 1, 1); STG_A(1, 1, 1);
    VM0();
    BAR();
    LDA(af0, 0, 0); LDB(bfr0, 0, 0);         // operands for P1's MM

    // ---- main loop: 7 iterations, tiles (2t in s0, 2t+1 in s1) ----
    #pragma unroll 1
    for (int t = 0; t < 7; ++t) {
        const int ka = 2 * t + 1, kb2 = 2 * t + 2, kc = 2 * t + 3;
        // P1
        MM(0, 0, af0, bfr0);
        LDB(bfr1, 0, 1); STG_B(1, 0, ka);                        BAR();
        // P2
        MM(0, 1, af0, bfr1);
        LDA(af1, 0, 1); STG_A(0, 0, kb2);                        BAR();
        // P3
        MM(1, 1, af1, bfr1); STG_B(0, 1, kb2); VM2();            BAR();
        // P4  (s1/tile-ka reads: safe behind P3's VM2+BAR)
        MM(1, 0, af1, bfr0);
        LDA(af0, 1, 0); LDB(bfr0, 1, 0); STG_A(0, 1, kb2);       BAR();
        // P5
        MM(0, 0, af0, bfr0);
        LDB(bfr1, 1, 1); STG_B(0, 0, kb2);                       BAR();
        // P6
        MM(0, 1, af0, bfr1);
        LDA(af1, 1, 1); STG_A(1, 0, kc);                         BAR();
        // P7
        MM(1, 1, af1, bfr1); STG_B(1, 1, kc); VM2();             BAR();
        // P8  (s0/tile-kb2 reads: safe behind P7's VM2+BAR)
        MM(1, 0, af1, bfr0);
        LDA(af0, 0, 0); LDB(bfr0, 0, 0); STG_A(1, 1, kc);        BAR();
    }
    // ---- tail: tiles 14 (s0), 15 (s1) ----
    MM(0, 0, af0, bfr0);
    LDB(bfr1, 0, 1); STG_B(1, 0, 15);                            BAR();
    MM(0, 1, af0, bfr1); LDA(af1, 0, 1);                         BAR();
    MM(1, 1, af1, bfr1); VM0();                                  BAR();
    MM(1, 0, af1, bfr0); LDA(af0, 1, 0); LDB(bfr0, 1, 0);        BAR();
    MM(0, 0, af0, bfr0); LDB(bfr1, 1, 1);                        BAR();
    MM(0, 1, af0, bfr1); LDA(af1, 1, 1);                         BAR();
    MM(1, 1, af1, bfr1);                                         BAR();
    MM(1, 0, af1, bfr0);

    // ---- epilogue: acc*2^-12 + rs*csum + bias, sigmoid, NT stores ----
    // C/D layout: col=lane&15, row=(lane>>4)*4+reg  [m89/m91]
    const float inv = 1.0f / 4096.0f;               // undo 64*64 scaling
    const int grp = nt >> 1;                        // 0=q, 1=s, 2=k
    const float* bias = (grp == 0) ? bq : ((grp == 1) ? bs : bk);
    float* obase = out + (size_t)grp * ((size_t)BATCH_N * 512);
    const int cb = (nt & 1) * 256;
    #pragma unroll
    for (int qb = 0; qb < 2; ++qb)
        #pragma unroll
        for (int j = 0; j < 2; ++j) {
            const int coll = cb + qb * 128 + wn * 32 + j * 16 + r16;
            const float bv = bias[coll];
            const float cv = csum[n0 + qb * 128 + wn * 32 + j * 16 + r16];
            #pragma unroll
            for (int qa = 0; qa < 2; ++qa)
                #pragma unroll
                for (int i = 0; i < 4; ++i) {
                    const int rbase = m0 + qa * 128 + wm * 64 + i * 16 + ((lane >> 4) << 2);
                    const float4 rv = *(const float4*)(rs + rbase);
                    #pragma unroll
                    for (int r = 0; r < 4; ++r) {
                        const float rsv = (r == 0) ? rv.x : (r == 1) ? rv.y : (r == 2) ? rv.z : rv.w;
                        float v = acc[qa * 4 + i][qb * 2 + j][r] * inv + rsv * cv + bv;
                        v = 1.0f / (1.0f + __expf(-v));
                        __builtin_nontemporal_store(v, &obase[(size_t)(rbase + r) * 512 + coll]);
                    }
                }
        }
#undef STG_A
#undef STG_B
#undef LDA
#undef LDB
#undef MM
}

extern "C" void kernel_launch(void* const* d_in, const int* in_sizes, int n_in,
                              void* d_out, int out_size, void* d_ws, size_t ws_size,
                              hipStream_t stream) {
    const int*   ids = (const int*)d_in[0];
    const float* mem = (const float*)d_in[1];
    const float* emb = (const float*)d_in[2];
    const float* Wq  = (const float*)d_in[3];
    const float* bq  = (const float*)d_in[4];
    const float* Ws  = (const float*)d_in[5];
    const float* bs  = (const float*)d_in[6];
    const float* Wk  = (const float*)d_in[7];
    const float* bk  = (const float*)d_in[8];
    float* out = (float*)d_out;

    unsigned char* x  = (unsigned char*)d_ws;                 // 64 MiB fp8
    unsigned char* wt = x + (size_t)BATCH_N * KDIM;           // 1.5 MiB fp8
    float* csum = (float*)(wt + (size_t)NTOT * KDIM);         // 6 KiB
    float* rs   = csum + NTOT;                                // 256 KiB

    hipLaunchKernelGGL(wconv_kernel, dim3(NTOT), dim3(256), 0, stream, Wq, Ws, Wk, wt);
    hipLaunchKernelGGL(colsum_kernel, dim3(6), dim3(256), 0, stream, Wq, Ws, Wk, csum);
    hipLaunchKernelGGL(prep_kernel, dim3(BATCH_N / 4), dim3(256), 0, stream, ids, mem, emb, x, rs);
    hipLaunchKernelGGL(gemm_kernel, dim3(NWG), dim3(512), 0, stream,
                       x, wt, csum, rs, bq, bs, bk, out);
}

// Round 18
// 354.895 us; speedup vs baseline: 1.1117x; 1.1117x over previous
//
#include <hip/hip_runtime.h>
#include <hip/hip_bf16.h>
#include <stdint.h>

#define BATCH_N 65536
#define KDIM 1024
#define NTOT 1536

typedef long long i64;
typedef i64 i64x2 __attribute__((ext_vector_type(2)));
typedef float f32x4 __attribute__((ext_vector_type(4)));

// pack 4 floats (scaled) into 4 fp8-e4m3 bytes
__device__ __forceinline__ unsigned pk4(float4 f, float s) {
    int w = __builtin_amdgcn_cvt_pk_fp8_f32(f.x * s, f.y * s, 0, false);
    w = __builtin_amdgcn_cvt_pk_fp8_f32(f.z * s, f.w * s, w, true);
    return (unsigned)w;
}

// ---------------------------------------------------------------------------
// fp8 k-permuted row layout (per 64-B K-tile).  Key m = (row>>1)&3  [r18 fix:
// was row&3, whose bit0 aliased the row-parity bank bit -> only 4 of 8 bank
// quads per quarter-wave, 4-way conflict].  Position
//   P = kt*64 + 16*(g ^ m) + 8u + low   holds   k = kt*64 + 32u + 8g + low.
// GEMM fragment read: lane (r16, gk=lane>>4) reads ONE aligned 16-B word at
// row*64 + 16*(gk ^ ((r16>>1)&3)) -> {kk0 8B, kk1 8B}.  Bank quad =
// 16*(r16&1) + 4*(gk^((r16>>1)&3)): per quarter-wave (fixed gk) the pair
// (r16&1,(r16>>1)&3) covers all 8 quads x 2 lanes -> conflict-free (bf16
// geometry).
// ---------------------------------------------------------------------------

// Kernel 1: E[b][k] = emb[id_b][k]*64 fp8, permuted layout; rs[b] = rowsum.
__global__ __launch_bounds__(256) void prep_kernel(
    const int* __restrict__ ids,
    const float* __restrict__ mem,
    const float* __restrict__ emb,
    unsigned char* __restrict__ x,
    float* __restrict__ rs)
{
    const int b    = blockIdx.x * 4 + (threadIdx.x >> 6);
    const int lane = threadIdx.x & 63;
    const int id   = ids[b];
    const float4* m4 = (const float4*)(mem + (size_t)id * KDIM) + lane;
    float4 v0 = m4[0], v1 = m4[64], v2 = m4[128], v3 = m4[192];
    float s = (v0.x + v0.y + v0.z + v0.w) + (v1.x + v1.y + v1.z + v1.w)
            + (v2.x + v2.y + v2.z + v2.w) + (v3.x + v3.y + v3.z + v3.w);
    #pragma unroll
    for (int off = 1; off < 64; off <<= 1) s += __shfl_xor(s, off, 64);
    if (lane == 0) rs[b] = s;

    // lane owns k = lane*16 .. +15:  kt = lane>>2, u = (lane>>1)&1,
    // halves h=0,1 -> g = 2*(lane&1) + h
    const float4* e4 = (const float4*)(emb + (size_t)id * KDIM) + lane * 4;
    float4 f0 = e4[0], f1 = e4[1], f2 = e4[2], f3 = e4[3];
    uint2 half0 = {pk4(f0, 64.f), pk4(f1, 64.f)};   // k +0..7
    uint2 half1 = {pk4(f2, 64.f), pk4(f3, 64.f)};   // k +8..15
    const int kt = lane >> 2;
    const int u  = (lane >> 1) & 1;
    const int g0 = 2 * (lane & 1);
    const int m  = (b >> 1) & 3;                    // r18: was b & 3
    unsigned char* rowp = x + (size_t)b * KDIM + kt * 64 + 8 * u;
    *(uint2*)(rowp + 16 * (g0 ^ m))       = half0;
    *(uint2*)(rowp + 16 * ((g0 + 1) ^ m)) = half1;
}

// Kernel 2: Wt[n] = W_{n/512}[.][n%512]*64 fp8, same permuted layout.
__global__ __launch_bounds__(256) void wconv_kernel(
    const float* __restrict__ Wq, const float* __restrict__ Ws,
    const float* __restrict__ Wk, unsigned char* __restrict__ wt)
{
    const int gt  = blockIdx.x * 256 + threadIdx.x;   // 0..393215
    const int n   = gt % NTOT;
    const int kb4 = (gt / NTOT) * 4;
    const float* W = (n < 512) ? Wq : ((n < 1024) ? Ws : Wk);
    const int nn = n & 511;
    float4 f;
    f.x = W[(size_t)(kb4 + 0) * 512 + nn];
    f.y = W[(size_t)(kb4 + 1) * 512 + nn];
    f.z = W[(size_t)(kb4 + 2) * 512 + nn];
    f.w = W[(size_t)(kb4 + 3) * 512 + nn];
    const unsigned w = pk4(f, 64.f);
    const int kt = kb4 >> 6, kl = kb4 & 63;
    const int u = (kl >> 5) & 1, g = (kl >> 3) & 3, low = kl & 7;
    const int dst = kt * 64 + 16 * (g ^ ((n >> 1) & 3)) + 8 * u + low;  // r18
    *(unsigned*)(wt + (size_t)n * KDIM + dst) = w;
}

// Kernel 2b: colsum stage 1 -- part[s][n] = sum of 64-row k-slab s, column n.
// 96 blocks (16 slabs x 6 n-chunks), wave-coalesced loads.  Deterministic.
__global__ __launch_bounds__(256) void colsum1_kernel(
    const float* __restrict__ Wq, const float* __restrict__ Ws,
    const float* __restrict__ Wk, float* __restrict__ part)
{
    const int t = threadIdx.x;
    const int s = blockIdx.x / 6;            // k-slab 0..15
    const int c = blockIdx.x % 6;            // n-chunk 0..5
    const float* W = (c < 2) ? Wq : ((c < 4) ? Ws : Wk);
    const float* p = W + (size_t)(s * 64) * 512 + (c & 1) * 256 + t;
    float s0 = 0.f, s1 = 0.f, s2 = 0.f, s3 = 0.f;
    #pragma unroll
    for (int i = 0; i < 64; i += 4) {
        s0 += p[(size_t)(i + 0) * 512];
        s1 += p[(size_t)(i + 1) * 512];
        s2 += p[(size_t)(i + 2) * 512];
        s3 += p[(size_t)(i + 3) * 512];
    }
    part[s * NTOT + c * 256 + t] = (s0 + s1) + (s2 + s3);
}

// Kernel 2c: colsum stage 2 -- csum[n] = sum over 16 slab partials.
__global__ __launch_bounds__(256) void colsum2_kernel(
    const float* __restrict__ part, float* __restrict__ csum)
{
    const int n = blockIdx.x * 256 + threadIdx.x;   // 6 blocks
    float s = 0.f;
    #pragma unroll
    for (int i = 0; i < 16; ++i) s += part[i * NTOT + n];
    csum[n] = s;
}

// ---------------------------------------------------------------------------
// Kernel 3: 256x256 8-phase fp8 GEMM (r17 skeleton; conflict-free fragment
// reads) + rank-1 + bias + sigmoid.
//   out = sigmoid( (E@W_fp8)*2^-12 + rs*csum + bias )
//   VM2 at P3/P7 (1 DMA/half-tile): at P3 in-flight={P1,P2,P3}, retires
//   B10(odd)+older -> tile o complete before P4's post-barrier reads; at P7
//   retires P2..P5 = tile 2t+2.  Counted waits only, never 0 mid-loop.
// ---------------------------------------------------------------------------
#define BM 256
#define BN 256
#define MT (BATCH_N / BM)   // 256
#define NT (NTOT / BN)      // 6
#define NWG (MT * NT)       // 1536 = 8 * 192, 192 % 6 == 0 -> bijective

#define BAR() asm volatile("s_barrier" ::: "memory")
#define VM2() asm volatile("s_waitcnt vmcnt(2)" ::: "memory")
#define VM0() asm volatile("s_waitcnt vmcnt(0)" ::: "memory")
#define AS1 __attribute__((address_space(1)))
#define AS3 __attribute__((address_space(3)))

__global__ __launch_bounds__(512, 2) void gemm_kernel(
    const unsigned char* __restrict__ X,    // [65536][1024] fp8, permuted
    const unsigned char* __restrict__ Wt,   // [1536][1024]  fp8, permuted
    const float* __restrict__ csum,         // [1536]
    const float* __restrict__ rs,           // [65536]
    const float* __restrict__ bq, const float* __restrict__ bs,
    const float* __restrict__ bk, float* __restrict__ out)
{
    __shared__ __align__(16) unsigned char sA[32768];   // 32 KiB
    __shared__ __align__(16) unsigned char sB[32768];   // 32 KiB

    const int tid  = threadIdx.x;
    const int xcd  = blockIdx.x & 7;
    const int idx  = blockIdx.x >> 3;
    const int wgid = xcd * (NWG / 8) + idx;
    const int nt   = wgid % NT;              // n fastest: A-panel L2 reuse
    const int mt   = wgid / NT;
    const int m0   = mt * BM;
    const int n0   = nt * BN;
    const int wid  = tid >> 6;
    const int lane = tid & 63;
    const int wm   = wid >> 2;               // 0..1
    const int wn   = wid & 3;                // 0..3
    const int r16  = lane & 15;
    const int gk   = lane >> 4;              // 0..3 k-group
    const int fsw  = 16 * (gk ^ ((r16 >> 1) & 3));   // r18: was r16&3

    f32x4 acc[8][4];
    #pragma unroll
    for (int i = 0; i < 8; i++)
        #pragma unroll
        for (int j = 0; j < 4; j++)
            acc[i][j] = f32x4{0.f, 0.f, 0.f, 0.f};

    i64 af0[4][2], af1[4][2], bfr0[2][2], bfr1[2][2];

    // staging source: row = tid>>2, 16B chunk = tid&3 (layout already permuted)
    const unsigned char* gA = X  + (size_t)(m0 + (tid >> 2)) * KDIM + (tid & 3) * 16;
    const unsigned char* gB = Wt + (size_t)(n0 + (tid >> 2)) * KDIM + (tid & 3) * 16;
    const int ldst = tid * 16;               // linear LDS dest

// stage ONE half-tile (1 DMA instr/thread, 128 rows x 64 B)
#define STG_A(slot, h, kt) \
    __builtin_amdgcn_global_load_lds( \
        (const AS1 void*)(gA + (size_t)(h) * 128 * KDIM + (kt) * 64), \
        (AS3 void*)(&sA[((slot) * 2 + (h)) * 8192 + ldst]), 16, 0, 0)
#define STG_B(slot, h, kt) \
    __builtin_amdgcn_global_load_lds( \
        (const AS1 void*)(gB + (size_t)(h) * 128 * KDIM + (kt) * 64), \
        (AS3 void*)(&sB[((slot) * 2 + (h)) * 8192 + ldst]), 16, 0, 0)

#define LDA(SET, slot, qa) do {                                                 \
    const char* p = (const char*)&sA[((slot) * 2 + (qa)) * 8192];                \
    _Pragma("unroll")                                                            \
    for (int i = 0; i < 4; ++i) {                                                \
        i64x2 v = *(const i64x2*)(p + (wm * 64 + i * 16 + r16) * 64 + fsw);      \
        SET[i][0] = v[0]; SET[i][1] = v[1];                                      \
    }                                                                            \
} while (0)
#define LDB(SET, slot, qb) do {                                                 \
    const char* p = (const char*)&sB[((slot) * 2 + (qb)) * 8192];                \
    _Pragma("unroll")                                                            \
    for (int j = 0; j < 2; ++j) {                                                \
        i64x2 v = *(const i64x2*)(p + (wn * 32 + j * 16 + r16) * 64 + fsw);      \
        SET[j][0] = v[0]; SET[j][1] = v[1];                                      \
    }                                                                            \
} while (0)

#define MM(QA, QB, ASET, BSET) do {                                             \
    __builtin_amdgcn_s_setprio(1);                                               \
    _Pragma("unroll")                                                            \
    for (int i = 0; i < 4; ++i)                                                  \
        _Pragma("unroll")                                                        \
        for (int j = 0; j < 2; ++j)                                              \
            _Pragma("unroll")                                                    \
            for (int kk = 0; kk < 2; ++kk)                                       \
                acc[(QA) * 4 + i][(QB) * 2 + j] =                                \
                    __builtin_amdgcn_mfma_f32_16x16x32_fp8_fp8(                  \
                        ASET[i][kk], BSET[j][kk],                                \
                        acc[(QA) * 4 + i][(QB) * 2 + j], 0, 0, 0);               \
    __builtin_amdgcn_s_setprio(0);                                               \
} while (0)

    // ---- prologue: tile0 full (s0) + tile1 {Ah0,Bh1,Ah1} (s1) ----
    STG_A(0, 0, 0); STG_A(0, 1, 0); STG_B(0, 0, 0); STG_B(0, 1, 0);
    STG_A(1, 0, 1); STG_B(1, 1, 1); STG_A(1, 1, 1);
    VM0();
    BAR();
    LDA(af0, 0, 0); LDB(bfr0, 0, 0);         // operands for P1's MM

    // ---- main loop: 7 iterations, tiles (2t in s0, 2t+1 in s1) ----
    #pragma unroll 1
    for (int t = 0; t < 7; ++t) {
        const int ka = 2 * t + 1, kb2 = 2 * t + 2, kc = 2 * t + 3;
        // P1
        MM(0, 0, af0, bfr0);
        LDB(bfr1, 0, 1); STG_B(1, 0, ka);                        BAR();
        // P2
        MM(0, 1, af0, bfr1);
        LDA(af1, 0, 1); STG_A(0, 0, kb2);                        BAR();
        // P3
        MM(1, 1, af1, bfr1); STG_B(0, 1, kb2); VM2();            BAR();
        // P4  (s1/tile-ka reads: safe behind P3's VM2+BAR)
        MM(1, 0, af1, bfr0);
        LDA(af0, 1, 0); LDB(bfr0, 1, 0); STG_A(0, 1, kb2);       BAR();
        // P5
        MM(0, 0, af0, bfr0);
        LDB(bfr1, 1, 1); STG_B(0, 0, kb2);                       BAR();
        // P6
        MM(0, 1, af0, bfr1);
        LDA(af1, 1, 1); STG_A(1, 0, kc);                         BAR();
        // P7
        MM(1, 1, af1, bfr1); STG_B(1, 1, kc); VM2();             BAR();
        // P8  (s0/tile-kb2 reads: safe behind P7's VM2+BAR)
        MM(1, 0, af1, bfr0);
        LDA(af0, 0, 0); LDB(bfr0, 0, 0); STG_A(1, 1, kc);        BAR();
    }
    // ---- tail: tiles 14 (s0), 15 (s1) ----
    MM(0, 0, af0, bfr0);
    LDB(bfr1, 0, 1); STG_B(1, 0, 15);                            BAR();
    MM(0, 1, af0, bfr1); LDA(af1, 0, 1);                         BAR();
    MM(1, 1, af1, bfr1); VM0();                                  BAR();
    MM(1, 0, af1, bfr0); LDA(af0, 1, 0); LDB(bfr0, 1, 0);        BAR();
    MM(0, 0, af0, bfr0); LDB(bfr1, 1, 1);                        BAR();
    MM(0, 1, af0, bfr1); LDA(af1, 1, 1);                         BAR();
    MM(1, 1, af1, bfr1);                                         BAR();
    MM(1, 0, af1, bfr0);

    // ---- epilogue: acc*2^-12 + rs*csum + bias, sigmoid, NT stores ----
    // C/D layout: col=lane&15, row=(lane>>4)*4+reg  [m89/m91]
    const float inv = 1.0f / 4096.0f;               // undo 64*64 scaling
    const int grp = nt >> 1;                        // 0=q, 1=s, 2=k
    const float* bias = (grp == 0) ? bq : ((grp == 1) ? bs : bk);
    float* obase = out + (size_t)grp * ((size_t)BATCH_N * 512);
    const int cb = (nt & 1) * 256;
    #pragma unroll
    for (int qb = 0; qb < 2; ++qb)
        #pragma unroll
        for (int j = 0; j < 2; ++j) {
            const int coll = cb + qb * 128 + wn * 32 + j * 16 + r16;
            const float bv = bias[coll];
            const float cv = csum[n0 + qb * 128 + wn * 32 + j * 16 + r16];
            #pragma unroll
            for (int qa = 0; qa < 2; ++qa)
                #pragma unroll
                for (int i = 0; i < 4; ++i) {
                    const int rbase = m0 + qa * 128 + wm * 64 + i * 16 + ((lane >> 4) << 2);
                    const float4 rv = *(const float4*)(rs + rbase);
                    #pragma unroll
                    for (int r = 0; r < 4; ++r) {
                        const float rsv = (r == 0) ? rv.x : (r == 1) ? rv.y : (r == 2) ? rv.z : rv.w;
                        float v = acc[qa * 4 + i][qb * 2 + j][r] * inv + rsv * cv + bv;
                        v = 1.0f / (1.0f + __expf(-v));
                        __builtin_nontemporal_store(v, &obase[(size_t)(rbase + r) * 512 + coll]);
                    }
                }
        }
#undef STG_A
#undef STG_B
#undef LDA
#undef LDB
#undef MM
}

extern "C" void kernel_launch(void* const* d_in, const int* in_sizes, int n_in,
                              void* d_out, int out_size, void* d_ws, size_t ws_size,
                              hipStream_t stream) {
    const int*   ids = (const int*)d_in[0];
    const float* mem = (const float*)d_in[1];
    const float* emb = (const float*)d_in[2];
    const float* Wq  = (const float*)d_in[3];
    const float* bq  = (const float*)d_in[4];
    const float* Ws  = (const float*)d_in[5];
    const float* bs  = (const float*)d_in[6];
    const float* Wk  = (const float*)d_in[7];
    const float* bk  = (const float*)d_in[8];
    float* out = (float*)d_out;

    unsigned char* x  = (unsigned char*)d_ws;                 // 64 MiB fp8
    unsigned char* wt = x + (size_t)BATCH_N * KDIM;           // 1.5 MiB fp8
    float* csum = (float*)(wt + (size_t)NTOT * KDIM);         // 6 KiB
    float* rs   = csum + NTOT;                                // 256 KiB
    float* part = rs + BATCH_N;                               // 96 KiB

    hipLaunchKernelGGL(wconv_kernel, dim3(NTOT), dim3(256), 0, stream, Wq, Ws, Wk, wt);
    hipLaunchKernelGGL(colsum1_kernel, dim3(96), dim3(256), 0, stream, Wq, Ws, Wk, part);
    hipLaunchKernelGGL(colsum2_kernel, dim3(6), dim3(256), 0, stream, part, csum);
    hipLaunchKernelGGL(prep_kernel, dim3(BATCH_N / 4), dim3(256), 0, stream, ids, mem, emb, x, rs);
    hipLaunchKernelGGL(gemm_kernel, dim3(NWG), dim3(512), 0, stream,
                       x, wt, csum, rs, bq, bs, bk, out);
}